// Round 10
// baseline (875.304 us; speedup 1.0000x reference)
//
#include <hip/hip_runtime.h>
#include <hip/hip_bf16.h>

#define V1 4096
#define V2 2048
#define NNZ1 32768
#define NNZ2 16384
#define WCAP 48

typedef unsigned short u16;
typedef unsigned int u32;
typedef __attribute__((ext_vector_type(8))) short bf16x8;
typedef __attribute__((ext_vector_type(4))) float f32x4;

static __device__ __forceinline__ float bf2f(u16 u) {
  union { u32 i; float f; } c; c.i = ((u32)u) << 16; return c.f;
}
static __device__ __forceinline__ u16 f2bf(float f) {
  union { u32 i; float f; } c; c.f = f;
  u32 r = c.i + 0x7FFFu + ((c.i >> 16) & 1u);   // round-nearest-even
  return (u16)(r >> 16);
}

// ---------------- histogram + bf16 hi/lo weight transpose ----------------
// Wh/Wl[f][kap = k*32 + fin] = hi/lo bf16 split of W2[f][fin*25+k]
__global__ void k_hist(const int* __restrict__ L1r, const int* __restrict__ L2r,
                       const float* __restrict__ W2, u16* __restrict__ Wh,
                       u16* __restrict__ Wl,
                       int* __restrict__ cnt1, int* __restrict__ cnt2) {
  int lt = blockIdx.x, t = threadIdx.x;
  if (lt < 128) {
    atomicAdd(&cnt1[L1r[lt * 256 + t]], 1);
  } else if (lt < 192) {
    atomicAdd(&cnt2[L2r[(lt - 128) * 256 + t]], 1);
  } else {
    int idx = (lt - 192) * 256 + t;          // 51200 = 64 f x 800 kap
    int f = idx / 800;
    int kap = idx - f * 800;
    int k = kap >> 5, fin = kap & 31;
    float w = W2[f * 800 + fin * 25 + k];
    u16 hi = f2bf(w);
    Wh[idx] = hi;
    Wl[idx] = f2bf(w - bf2f(hi));
  }
}

// ---------------- scan + degree counting-sort (descending) ----------------
__global__ void k_scan(int* __restrict__ cnt1, int* __restrict__ rs1,
                       int* __restrict__ cnt2, int* __restrict__ rs2,
                       int* __restrict__ slotOf1, int* __restrict__ rowOf1,
                       int* __restrict__ slotOf2, int* __restrict__ rowOf2) {
  __shared__ int sums[256];
  __shared__ int degS[V1];
  __shared__ int hist[64];
  __shared__ int hb[64];
  int t = threadIdx.x;
  int* cnt; int* rs; int* slotOf; int* rowOf; int V, NT, nnz;
  if (blockIdx.x == 0) { cnt = cnt1; rs = rs1; slotOf = slotOf1; rowOf = rowOf1; V = V1; NT = 1024; nnz = NNZ1; }
  else                 { cnt = cnt2; rs = rs2; slotOf = slotOf2; rowOf = rowOf2; V = V2; NT = 512;  nnz = NNZ2; }
  int chunk = V / 256, base = t * chunk, s = 0;
  for (int i = 0; i < chunk; ++i) { int c = cnt[base + i]; degS[base + i] = c; s += c; }
  sums[t] = s;
  if (t < 64) hist[t] = 0;
  __syncthreads();
  if (t == 0) {
    int run = 0;
    for (int i = 0; i < 256; ++i) { int c = sums[i]; sums[i] = run; run += c; }
  }
  __syncthreads();
  int pfx = sums[t];
  for (int i = 0; i < chunk; ++i) {
    int c = degS[base + i];
    rs[base + i] = pfx;
    cnt[base + i] = pfx;                     // cursor for scatter
    pfx += c;
  }
  if (t == 0) rs[V] = nnz;
  for (int i = 0; i < chunk; ++i) {
    int d = degS[base + i]; if (d > 63) d = 63;
    atomicAdd(&hist[d], 1);
  }
  __syncthreads();
  if (t == 0) {
    int run = 0;
    for (int d = 63; d >= 0; --d) { hb[d] = run; run += hist[d]; }
  }
  __syncthreads();
  for (int i = 0; i < chunk; ++i) {
    int v = base + i;
    int d = degS[v]; if (d > 63) d = 63;
    int r = atomicAdd(&hb[d], 1);            // rank, degree-descending
    int slot = (r & 3) * NT + (r >> 2);
    slotOf[v] = slot;
    rowOf[slot] = v;
  }
}

// ---------------- scatter edges directly into zero-padded ELL ----------------
// ell[w*V + slot] = (val, as_float(col*byte_mult)); w = CSR position in row so
// per-row FP summation order matches the reference CSR order exactly.
__global__ void k_scatter(const int* __restrict__ L1r, const int* __restrict__ L1c,
                          const float* __restrict__ L1v,
                          const int* __restrict__ L2r, const int* __restrict__ L2c,
                          const float* __restrict__ L2v,
                          int* __restrict__ cur1, const int* __restrict__ rs1,
                          const int* __restrict__ slotOf1, float2* __restrict__ ell1,
                          int* __restrict__ cur2, const int* __restrict__ rs2,
                          const int* __restrict__ slotOf2, float2* __restrict__ ell2) {
  int lt = blockIdx.x, t = threadIdx.x;
  if (lt < 128) {
    int e = lt * 256 + t;
    int row = L1r[e];
    int pos = atomicAdd(&cur1[row], 1);
    int w = pos - rs1[row];
    if (w < WCAP)
      ell1[(size_t)w * V1 + slotOf1[row]] = make_float2(L1v[e], __int_as_float(L1c[e] * 4));
  } else {
    int e = (lt - 128) * 256 + t;
    int row = L2r[e];
    int pos = atomicAdd(&cur2[row], 1);
    int w = pos - rs2[row];
    if (w < WCAP)
      ell2[(size_t)w * V2 + slotOf2[row]] = make_float2(L2v[e], __int_as_float(L2c[e] * 16));
  }
}

// ---------------- layer-1 recurrence: double-buffered state, 1 barrier/step ----------------
// fa[A] = T_{k-1} (gather source), fa[B] = T_k (write target). Disjoint
// buffers -> no intra-step barrier; single barrier before the pack/swap.
__global__ void __launch_bounds__(1024) k_l1rec(
    const float* __restrict__ x, const int* __restrict__ rs1,
    const int* __restrict__ rowOf1, const float2* __restrict__ ell1,
    u16* __restrict__ T1) {
  __shared__ float fa[2][V1];
  const int b = blockIdx.x, t = threadIdx.x;
#pragma unroll
  for (int j = 0; j < 4; ++j) {
    int v = t + j * 1024;
    float xv = x[(size_t)b * V1 + v];
    fa[0][v] = xv;
    T1[((size_t)b) * V1 + v] = f2bf(xv);          // slice k=0
  }
  int vj[4];
#pragma unroll
  for (int j = 0; j < 4; ++j) vj[j] = rowOf1[t + j * 1024];
  int bound = rs1[vj[0] + 1] - rs1[vj[0]];
  if (bound > WCAP) bound = WCAP;
  float t2r[4];
  __syncthreads();
  int cur = 0;
  for (int k = 1; k < 25; ++k) {
    const float* A = fa[cur];
    float* Bf = fa[cur ^ 1];
    float acc[4] = {0.f, 0.f, 0.f, 0.f};
    for (int w = 0; w < bound; ++w) {
      const float2* ep = ell1 + (size_t)w * V1 + t;
#pragma unroll
      for (int j = 0; j < 4; ++j) {
        float2 ev = ep[j * 1024];
        int ub = __float_as_int(ev.y);            // col*4 (byte offset)
        float av = *(const float*)((const char*)A + ub);
        acc[j] = fmaf(ev.x, av, acc[j]);
      }
    }
#pragma unroll
    for (int j = 0; j < 4; ++j) {
      float old = A[vj[j]];
      float z = acc[j] - old;                     // coef = 2/lmax = 1
      if (k > 1) z = 2.f * z - t2r[j];
      t2r[j] = old;
      Bf[vj[j]] = z;
    }
    __syncthreads();                              // B complete; A reads done
#pragma unroll
    for (int j = 0; j < 4; ++j) {
      int v = t + j * 1024;
      T1[((size_t)k * 64 + b) * V1 + v] = f2bf(Bf[v]);
    }
    cur ^= 1;
  }
}

// ---------------- conv1 dense + relu + pool -> z0 [b][v2][32] ----------------
__global__ void k_conv1(const u16* __restrict__ T1, const float* __restrict__ W1,
                        const float* __restrict__ b1, float* __restrict__ z0) {
  __shared__ float w1s[800];
  __shared__ float b1s[32];
  const int b = blockIdx.x & 63, uc = blockIdx.x >> 6, t = threadIdx.x;
  for (int idx = t; idx < 800; idx += 256) w1s[idx] = W1[idx];
  if (t < 32) b1s[t] = b1[t];
  __syncthreads();
  const int u = uc * 256 + t;
  float a1[25], a2[25];
#pragma unroll
  for (int k = 0; k < 25; ++k) {
    u32 w = *(const u32*)&T1[((size_t)k * 64 + b) * V1 + 2 * u];
    a1[k] = bf2f((u16)w);
    a2[k] = bf2f((u16)(w >> 16));
  }
  float mout[32];
#pragma unroll
  for (int f = 0; f < 32; ++f) {
    float s1 = b1s[f], s2 = b1s[f];
#pragma unroll
    for (int k = 0; k < 25; ++k) {
      float w = w1s[f * 25 + k];
      s1 = fmaf(a1[k], w, s1);
      s2 = fmaf(a2[k], w, s2);
    }
    mout[f] = fmaxf(fmaxf(s1, 0.f), fmaxf(s2, 0.f));
  }
  float4* dst = (float4*)&z0[((size_t)b * V2 + u) * 32];
#pragma unroll
  for (int q = 0; q < 8; ++q)
    dst[q] = make_float4(mout[4 * q], mout[4 * q + 1], mout[4 * q + 2], mout[4 * q + 3]);
}

// ---------------- layer-2 recurrence: double-buffered state, 1 barrier/step ----------------
// TkS[2][v][4] fp32 (64 KB -> 2 blocks/CU). Gather from A, write T_k to B
// (disjoint -> no intra-step barrier), one barrier, pack B -> T2, swap.
// T2 layout [k*8+fg][m = bl*V2 + v][4fin] bf16 -> contiguous 8B x 64 stores.
__global__ void __launch_bounds__(512, 4) k_l2rec(
    const float* __restrict__ z0, const int* __restrict__ rs2,
    const int* __restrict__ rowOf2, const float2* __restrict__ ell2,
    u16* __restrict__ T2, int b0, int bs) {
  __shared__ float TkS[2][V2 * 4];
  const int bl = blockIdx.x % bs, fg = blockIdx.x / bs;   // fg in [0,8)
  const int b = b0 + bl, f0 = fg * 4;
  const int t = threadIdx.x;
  const size_t M = (size_t)bs * V2;
  const size_t mb = (size_t)bl * V2;
#pragma unroll
  for (int j = 0; j < 4; ++j) {
    int v = t + j * 512;
    float4 xv = *(const float4*)&z0[((size_t)b * V2 + v) * 32 + f0];
    *(float4*)&TkS[0][v * 4] = xv;
    u32 lo = (u32)f2bf(xv.x) | ((u32)f2bf(xv.y) << 16);
    u32 hi = (u32)f2bf(xv.z) | ((u32)f2bf(xv.w) << 16);
    *(uint2*)&T2[((size_t)fg * M + mb + v) * 4] = make_uint2(lo, hi);
  }
  int vj[4];
#pragma unroll
  for (int j = 0; j < 4; ++j) vj[j] = rowOf2[t + j * 512];
  int bound = rs2[vj[0] + 1] - rs2[vj[0]];
  if (bound > WCAP) bound = WCAP;
  float4 t2r[4];
  __syncthreads();
  int cur = 0;
  for (int k = 1; k < 25; ++k) {
    const float* A = TkS[cur];
    float* Bf = TkS[cur ^ 1];
    float4 acc[4];
#pragma unroll
    for (int j = 0; j < 4; ++j) acc[j] = make_float4(0.f, 0.f, 0.f, 0.f);
    for (int w = 0; w < bound; ++w) {
      const float2* ep = ell2 + (size_t)w * V2 + t;
#pragma unroll
      for (int j = 0; j < 4; ++j) {
        float2 ev = ep[j * 512];
        int ub = __float_as_int(ev.y);            // col*16 (byte offset)
        float4 tv = *(const float4*)((const char*)A + ub);
        acc[j].x = fmaf(ev.x, tv.x, acc[j].x);
        acc[j].y = fmaf(ev.x, tv.y, acc[j].y);
        acc[j].z = fmaf(ev.x, tv.z, acc[j].z);
        acc[j].w = fmaf(ev.x, tv.w, acc[j].w);
      }
    }
#pragma unroll
    for (int j = 0; j < 4; ++j) {
      float4 old = *(const float4*)&A[vj[j] * 4];
      float4 z;
      z.x = acc[j].x - old.x; z.y = acc[j].y - old.y;
      z.z = acc[j].z - old.z; z.w = acc[j].w - old.w;
      if (k > 1) {
        z.x = 2.f * z.x - t2r[j].x; z.y = 2.f * z.y - t2r[j].y;
        z.z = 2.f * z.z - t2r[j].z; z.w = 2.f * z.w - t2r[j].w;
      }
      t2r[j] = old;
      *(float4*)&Bf[vj[j] * 4] = z;
    }
    __syncthreads();                              // B complete; A reads done
#pragma unroll
    for (int j = 0; j < 4; ++j) {
      int v = t + j * 512;
      float4 zz = *(const float4*)&Bf[v * 4];
      u32 lo = (u32)f2bf(zz.x) | ((u32)f2bf(zz.y) << 16);
      u32 hi = (u32)f2bf(zz.z) | ((u32)f2bf(zz.w) << 16);
      *(uint2*)&T2[(((size_t)k * 8 + fg) * M + mb + v) * 4] = make_uint2(lo, hi);
    }
    cur ^= 1;
  }
}

// ---------------- conv2 via MFMA: C = T2 * (Wh+Wl)^T, relu + pool -> h2h/h2l ----------------
__global__ void __launch_bounds__(256) k_conv2mm(
    const u16* __restrict__ T2, const u16* __restrict__ Wh, const u16* __restrict__ Wl,
    const float* __restrict__ b2, u16* __restrict__ h2h, u16* __restrict__ h2l,
    int b0, int bs) {
  const int t = threadIdx.x;
  const int wid = t >> 6, lane = t & 63;
  const int ln = lane & 15, kg = lane >> 4;
  const size_t M = (size_t)bs * V2;
  const int mBlk = blockIdx.x * 128;       // 128 rows per block, never crosses batch
  const int bl = mBlk >> 11;               // /V2
  const int v0 = mBlk & (V2 - 1);
  const int m0 = mBlk + wid * 32;          // wave's 2 strips
  const int vw = v0 + wid * 32;

  f32x4 acc[2][4];
#pragma unroll
  for (int nt = 0; nt < 4; ++nt) {
    float bv = b2[nt * 16 + ln];
    acc[0][nt] = (f32x4){bv, bv, bv, bv};
    acc[1][nt] = acc[0][nt];
  }

  for (int kc = 0; kc < 25; ++kc) {
    const int coff = kc * 32 + kg * 8;
    bf16x8 bh[4], blo[4];
#pragma unroll
    for (int nt = 0; nt < 4; ++nt) {
      bh[nt]  = *(const bf16x8*)(Wh + (size_t)(nt * 16 + ln) * 800 + coff);
      blo[nt] = *(const bf16x8*)(Wl + (size_t)(nt * 16 + ln) * 800 + coff);
    }
#pragma unroll
    for (int sp = 0; sp < 2; ++sp) {
      const u16* ap = T2 + ((size_t)(kc * 8 + kg * 2) * M + (size_t)(m0 + sp * 16 + ln)) * 4;
      uint2 alo = *(const uint2*)ap;
      uint2 ahi = *(const uint2*)(ap + M * 4);   // next fg-slab
      union { uint4 u; bf16x8 v; } ac;
      ac.u = make_uint4(alo.x, alo.y, ahi.x, ahi.y);
#pragma unroll
      for (int nt = 0; nt < 4; ++nt) {
        acc[sp][nt] = __builtin_amdgcn_mfma_f32_16x16x32_bf16(ac.v, bh[nt], acc[sp][nt], 0, 0, 0);
        acc[sp][nt] = __builtin_amdgcn_mfma_f32_16x16x32_bf16(ac.v, blo[nt], acc[sp][nt], 0, 0, 0);
      }
    }
  }
  const int b = b0 + bl;
  u16* hh = h2h + (size_t)b * 65536;
  u16* hl = h2l + (size_t)b * 65536;
#pragma unroll
  for (int sp = 0; sp < 2; ++sp) {
    int u = ((vw + sp * 16) >> 1) + kg * 2;
#pragma unroll
    for (int nt = 0; nt < 4; ++nt) {
      int f = nt * 16 + ln;
      float p0 = fmaxf(fmaxf(acc[sp][nt].x, acc[sp][nt].y), 0.f);
      float p1 = fmaxf(fmaxf(acc[sp][nt].z, acc[sp][nt].w), 0.f);
      u16 h0 = f2bf(p0), h1 = f2bf(p1);
      hh[(size_t)u * 64 + f] = h0;
      hh[(size_t)(u + 1) * 64 + f] = h1;
      hl[(size_t)u * 64 + f] = f2bf(p0 - bf2f(h0));
      hl[(size_t)(u + 1) * 64 + f] = f2bf(p1 - bf2f(h1));
    }
  }
}

// ---------------- fc1 via MFMA: partial products P[ksp][j][b] (no atomics) ----------------
__global__ void __launch_bounds__(256) k_fc1mm(
    const u16* __restrict__ h2h, const u16* __restrict__ h2l,
    const float* __restrict__ fW1, float* __restrict__ P) {
  __shared__ u16 ahS[64 * 128];   // [b][128 k] u16, byte ^= (b&7)<<4
  __shared__ u16 alS[64 * 128];
  const int t = threadIdx.x;
  const int wid = t >> 6, lane = t & 63;
  const int ln = lane & 15, kg = lane >> 4;
  const int jg = blockIdx.x & 7, ksp = blockIdx.x >> 3;   // 8 jg x 32 ksplits
  const int j = (jg * 4 + wid) * 16 + ln;                 // this lane's W row
  const int k0 = ksp * 2048;

  f32x4 acc[4];
#pragma unroll
  for (int bt = 0; bt < 4; ++bt) acc[bt] = (f32x4){0.f, 0.f, 0.f, 0.f};

  for (int sc = 0; sc < 16; ++sc) {
    const int kc = k0 + sc * 128;
    __syncthreads();                       // previous subchunk fully consumed
    for (int idx = t; idx < 1024; idx += 256) {
      int row = idx >> 4, unit = idx & 15;
      int lb = row * 256 + ((unit * 16) ^ ((row & 7) << 4));
      *(uint4*)((char*)ahS + lb) = *(const uint4*)(h2h + (size_t)row * 65536 + kc + unit * 8);
      *(uint4*)((char*)alS + lb) = *(const uint4*)(h2l + (size_t)row * 65536 + kc + unit * 8);
    }
    __syncthreads();
#pragma unroll
    for (int ks = 0; ks < 4; ++ks) {
      const float* wp = fW1 + (size_t)j * 65536 + kc + ks * 32 + kg * 8;
      float4 w0 = *(const float4*)wp;
      float4 w1 = *(const float4*)(wp + 4);
      float wa[8] = {w0.x, w0.y, w0.z, w0.w, w1.x, w1.y, w1.z, w1.w};
      bf16x8 bh, bl;
#pragma unroll
      for (int i = 0; i < 8; ++i) {
        u16 hi = f2bf(wa[i]);
        ((u16*)&bh)[i] = (short)hi;
        ((u16*)&bl)[i] = (short)f2bf(wa[i] - bf2f(hi));
      }
      const int kb = ks * 64 + kg * 16;
#pragma unroll
      for (int bt = 0; bt < 4; ++bt) {
        int row = bt * 16 + ln;
        int lb = row * 256 + (kb ^ ((row & 7) << 4));
        bf16x8 ah = *(const bf16x8*)((const char*)ahS + lb);
        bf16x8 al = *(const bf16x8*)((const char*)alS + lb);
        acc[bt] = __builtin_amdgcn_mfma_f32_16x16x32_bf16(ah, bh, acc[bt], 0, 0, 0);
        acc[bt] = __builtin_amdgcn_mfma_f32_16x16x32_bf16(ah, bl, acc[bt], 0, 0, 0);
        acc[bt] = __builtin_amdgcn_mfma_f32_16x16x32_bf16(al, bh, acc[bt], 0, 0, 0);
      }
    }
  }
#pragma unroll
  for (int bt = 0; bt < 4; ++bt) {
#pragma unroll
    for (int r = 0; r < 4; ++r) {
      P[(size_t)ksp * 32768 + (size_t)j * 64 + bt * 16 + kg * 4 + r] = acc[bt][r];
    }
  }
}

// ---------------- reduce fc1 partials: fc1o[jb] = sum_ksp P[ksp][jb] ----------------
__global__ void k_red(const float* __restrict__ P, float* __restrict__ fc1o) {
  int idx = blockIdx.x * 256 + threadIdx.x;
  float s = 0.f;
  for (int k = 0; k < 32; ++k) s += P[(size_t)k * 32768 + idx];
  fc1o[idx] = s;
}

__global__ void __launch_bounds__(256) k_fc2(
    const float* __restrict__ fc1o, const float* __restrict__ fb1,
    const float* __restrict__ fW2, const float* __restrict__ fb2,
    float* __restrict__ out) {
  __shared__ float red[256];
  const int c = blockIdx.x, t = threadIdx.x;
  const int b = t & 63, g = t >> 6;
  float s = 0.f;
  for (int j = g * 128; j < g * 128 + 128; ++j) {
    float a = fmaxf(fc1o[j * 64 + b] + fb1[j], 0.f);
    s = fmaf(a, fW2[c * 512 + j], s);
  }
  red[t] = s;
  __syncthreads();
  if (t < 64) {
    out[b * 10 + c] = red[t] + red[t + 64] + red[t + 128] + red[t + 192] + fb2[c];
  }
}

extern "C" void kernel_launch(void* const* d_in, const int* in_sizes, int n_in,
                              void* d_out, int out_size, void* d_ws, size_t ws_size,
                              hipStream_t stream) {
  const float* x    = (const float*)d_in[0];
  const int* L1r    = (const int*)d_in[1];
  const int* L1c    = (const int*)d_in[2];
  const float* L1v  = (const float*)d_in[3];
  const int* L2r    = (const int*)d_in[4];
  const int* L2c    = (const int*)d_in[5];
  const float* L2v  = (const float*)d_in[6];
  const float* W1   = (const float*)d_in[7];
  const float* b1   = (const float*)d_in[8];
  const float* W2   = (const float*)d_in[9];
  const float* b2   = (const float*)d_in[10];
  const float* fW1  = (const float*)d_in[11];
  const float* fb1  = (const float*)d_in[12];
  const float* fW2  = (const float*)d_in[13];
  const float* fb2  = (const float*)d_in[14];
  float* out = (float*)d_out;

  float* Wf = (float*)d_ws;
  size_t off = 0;
  auto alloc = [&](size_t n) { float* q = Wf + off; off += n; return q; };
  int* cnt1    = (int*)alloc(4096);
  int* rs1     = (int*)alloc(4104);     // padded to keep 16B alignment downstream
  int* cnt2    = (int*)alloc(2048);
  int* rs2     = (int*)alloc(2056);
  int* slotOf1 = (int*)alloc(4096);
  int* rowOf1  = (int*)alloc(4096);
  int* slotOf2 = (int*)alloc(2048);
  int* rowOf2  = (int*)alloc(2048);
  u16* Wh      = (u16*)alloc(25600);    // [64][800] bf16 hi (overalloc keeps alignment)
  u16* Wl      = (u16*)alloc(25600);    // [64][800] bf16 lo
  float* fc1o  = alloc(32768);
  float2* ell1 = (float2*)alloc((size_t)WCAP * V1 * 2);   // 1.5 MB
  float2* ell2 = (float2*)alloc((size_t)WCAP * V2 * 2);   // 0.75 MB
  float* P     = alloc(32 * 32768);     // fc1 partials, 4 MB
  float* z0    = alloc(4194304);        // [64 b][2048 v][32 f] fp32, 16.8 MB
  u16* h2h     = (u16*)alloc(2097152);  // [64 b][65536 i] bf16 hi, 8.4 MB
  u16* h2l     = (u16*)alloc(2097152);  // [64 b][65536 i] bf16 lo, 8.4 MB
  size_t fixedB = off * 4;

  // Batch split so the bf16 Chebyshev basis T2 fits the workspace.
  int ns = 8;
  for (int c = 1; c <= 8; c <<= 1) {
    size_t t2b = (size_t)V2 * (64 / c) * 800 * 2;
    size_t big = t2b > 16777216ull ? t2b : 16777216ull;   // T1 (12.6 MB) overlays same region
    if (fixedB + big + 65536 <= ws_size) { ns = c; break; }
  }
  const int bs = 64 / ns;
  u16* T1 = (u16*)(Wf + off);           // [k][b][v] bf16
  u16* T2 = (u16*)(Wf + off);           // [k*8+fg][m = bl*V2+v][4fin] bf16 — overlays T1 (dead)

  hipMemsetAsync(cnt1, 0, 4096 * sizeof(int), stream);
  hipMemsetAsync(cnt2, 0, 2048 * sizeof(int), stream);
  hipMemsetAsync(ell1, 0, (size_t)WCAP * V1 * 8, stream);  // padded ELL entries = 0
  hipMemsetAsync(ell2, 0, (size_t)WCAP * V2 * 8, stream);

  k_hist<<<392, 256, 0, stream>>>(L1r, L2r, W2, Wh, Wl, cnt1, cnt2);
  k_scan<<<2, 256, 0, stream>>>(cnt1, rs1, cnt2, rs2, slotOf1, rowOf1, slotOf2, rowOf2);
  k_scatter<<<192, 256, 0, stream>>>(L1r, L1c, L1v, L2r, L2c, L2v,
                                     cnt1, rs1, slotOf1, ell1,
                                     cnt2, rs2, slotOf2, ell2);

  k_l1rec<<<64, 1024, 0, stream>>>(x, rs1, rowOf1, ell1, T1);
  k_conv1<<<512, 256, 0, stream>>>(T1, W1, b1, z0);

  for (int s = 0; s < ns; ++s) {
    int b0 = s * bs;
    k_l2rec<<<bs * 8, 512, 0, stream>>>(z0, rs2, rowOf2, ell2, T2, b0, bs);  // 8 fin-groups of 4
    k_conv2mm<<<bs * 16, 256, 0, stream>>>(T2, Wh, Wl, b2, h2h, h2l, b0, bs);
  }

  k_fc1mm<<<256, 256, 0, stream>>>(h2h, h2l, fW1, P);
  k_red<<<128, 256, 0, stream>>>(P, fc1o);
  k_fc2<<<10, 256, 0, stream>>>(fc1o, fb1, fW2, fb2, out);
}

// Round 11
// 695.104 us; speedup vs baseline: 1.2592x; 1.2592x over previous
//
#include <hip/hip_runtime.h>
#include <hip/hip_bf16.h>

#define V1 4096
#define V2 2048
#define NNZ1 32768
#define NNZ2 16384
#define WCAP 48

typedef unsigned short u16;
typedef unsigned int u32;
typedef __attribute__((ext_vector_type(8))) short bf16x8;
typedef __attribute__((ext_vector_type(4))) float f32x4;

static __device__ __forceinline__ float bf2f(u16 u) {
  union { u32 i; float f; } c; c.i = ((u32)u) << 16; return c.f;
}
static __device__ __forceinline__ u16 f2bf(float f) {
  union { u32 i; float f; } c; c.f = f;
  u32 r = c.i + 0x7FFFu + ((c.i >> 16) & 1u);   // round-nearest-even
  return (u16)(r >> 16);
}

// ---------------- histogram + bf16 hi/lo weight transpose ----------------
// Wh/Wl[f][kap = k*32 + fin] = hi/lo bf16 split of W2[f][fin*25+k]
__global__ void k_hist(const int* __restrict__ L1r, const int* __restrict__ L2r,
                       const float* __restrict__ W2, u16* __restrict__ Wh,
                       u16* __restrict__ Wl,
                       int* __restrict__ cnt1, int* __restrict__ cnt2) {
  int lt = blockIdx.x, t = threadIdx.x;
  if (lt < 128) {
    atomicAdd(&cnt1[L1r[lt * 256 + t]], 1);
  } else if (lt < 192) {
    atomicAdd(&cnt2[L2r[(lt - 128) * 256 + t]], 1);
  } else {
    int idx = (lt - 192) * 256 + t;          // 51200 = 64 f x 800 kap
    int f = idx / 800;
    int kap = idx - f * 800;
    int k = kap >> 5, fin = kap & 31;
    float w = W2[f * 800 + fin * 25 + k];
    u16 hi = f2bf(w);
    Wh[idx] = hi;
    Wl[idx] = f2bf(w - bf2f(hi));
  }
}

// ---------------- scan + degree counting-sort (descending) ----------------
__global__ void k_scan(int* __restrict__ cnt1, int* __restrict__ rs1,
                       int* __restrict__ cnt2, int* __restrict__ rs2,
                       int* __restrict__ slotOf1, int* __restrict__ rowOf1,
                       int* __restrict__ slotOf2, int* __restrict__ rowOf2) {
  __shared__ int sums[256];
  __shared__ int degS[V1];
  __shared__ int hist[64];
  __shared__ int hb[64];
  int t = threadIdx.x;
  int* cnt; int* rs; int* slotOf; int* rowOf; int V, NT, nnz;
  if (blockIdx.x == 0) { cnt = cnt1; rs = rs1; slotOf = slotOf1; rowOf = rowOf1; V = V1; NT = 1024; nnz = NNZ1; }
  else                 { cnt = cnt2; rs = rs2; slotOf = slotOf2; rowOf = rowOf2; V = V2; NT = 512;  nnz = NNZ2; }
  int chunk = V / 256, base = t * chunk, s = 0;
  for (int i = 0; i < chunk; ++i) { int c = cnt[base + i]; degS[base + i] = c; s += c; }
  sums[t] = s;
  if (t < 64) hist[t] = 0;
  __syncthreads();
  if (t == 0) {
    int run = 0;
    for (int i = 0; i < 256; ++i) { int c = sums[i]; sums[i] = run; run += c; }
  }
  __syncthreads();
  int pfx = sums[t];
  for (int i = 0; i < chunk; ++i) {
    int c = degS[base + i];
    rs[base + i] = pfx;
    cnt[base + i] = pfx;                     // cursor for scatter
    pfx += c;
  }
  if (t == 0) rs[V] = nnz;
  for (int i = 0; i < chunk; ++i) {
    int d = degS[base + i]; if (d > 63) d = 63;
    atomicAdd(&hist[d], 1);
  }
  __syncthreads();
  if (t == 0) {
    int run = 0;
    for (int d = 63; d >= 0; --d) { hb[d] = run; run += hist[d]; }
  }
  __syncthreads();
  for (int i = 0; i < chunk; ++i) {
    int v = base + i;
    int d = degS[v]; if (d > 63) d = 63;
    int r = atomicAdd(&hb[d], 1);            // rank, degree-descending
    int slot = (r & 3) * NT + (r >> 2);
    slotOf[v] = slot;
    rowOf[slot] = v;
  }
}

// ---------------- scatter edges directly into zero-padded ELL ----------------
// ell[w*V + slot] = (val, as_float(col*byte_mult)); w = CSR position in row so
// per-row FP summation order matches the reference CSR order exactly.
__global__ void k_scatter(const int* __restrict__ L1r, const int* __restrict__ L1c,
                          const float* __restrict__ L1v,
                          const int* __restrict__ L2r, const int* __restrict__ L2c,
                          const float* __restrict__ L2v,
                          int* __restrict__ cur1, const int* __restrict__ rs1,
                          const int* __restrict__ slotOf1, float2* __restrict__ ell1,
                          int* __restrict__ cur2, const int* __restrict__ rs2,
                          const int* __restrict__ slotOf2, float2* __restrict__ ell2) {
  int lt = blockIdx.x, t = threadIdx.x;
  if (lt < 128) {
    int e = lt * 256 + t;
    int row = L1r[e];
    int pos = atomicAdd(&cur1[row], 1);
    int w = pos - rs1[row];
    if (w < WCAP)
      ell1[(size_t)w * V1 + slotOf1[row]] = make_float2(L1v[e], __int_as_float(L1c[e] * 4));
  } else {
    int e = (lt - 128) * 256 + t;
    int row = L2r[e];
    int pos = atomicAdd(&cur2[row], 1);
    int w = pos - rs2[row];
    if (w < WCAP)
      ell2[(size_t)w * V2 + slotOf2[row]] = make_float2(L2v[e], __int_as_float(L2c[e] * 16));
  }
}

// ---------------- layer-1 recurrence: block = one batch, ELL gather ----------------
__global__ void __launch_bounds__(1024) k_l1rec(
    const float* __restrict__ x, const int* __restrict__ rs1,
    const int* __restrict__ rowOf1, const float2* __restrict__ ell1,
    u16* __restrict__ T1) {
  __shared__ float fa[V1];
  const int b = blockIdx.x, t = threadIdx.x;
#pragma unroll
  for (int j = 0; j < 4; ++j) {
    int v = t + j * 1024;
    float xv = x[(size_t)b * V1 + v];
    fa[v] = xv;
    T1[((size_t)b) * V1 + v] = f2bf(xv);          // slice k=0
  }
  int vj[4];
#pragma unroll
  for (int j = 0; j < 4; ++j) vj[j] = rowOf1[t + j * 1024];
  int bound = rs1[vj[0] + 1] - rs1[vj[0]];
  if (bound > WCAP) bound = WCAP;
  float t2r[4];
  __syncthreads();
  for (int k = 1; k < 25; ++k) {
    float acc[4] = {0.f, 0.f, 0.f, 0.f};
    for (int w = 0; w < bound; ++w) {
      const float2* ep = ell1 + (size_t)w * V1 + t;
#pragma unroll
      for (int j = 0; j < 4; ++j) {
        float2 ev = ep[j * 1024];
        int ub = __float_as_int(ev.y);            // col*4 (byte offset)
        float av = *(const float*)((const char*)fa + ub);
        acc[j] = fmaf(ev.x, av, acc[j]);
      }
    }
    __syncthreads();
#pragma unroll
    for (int j = 0; j < 4; ++j) {
      float old = fa[vj[j]];
      float z = acc[j] - old;                     // coef = 2/lmax = 1
      if (k > 1) z = 2.f * z - t2r[j];
      t2r[j] = old;
      fa[vj[j]] = z;
    }
    __syncthreads();
#pragma unroll
    for (int j = 0; j < 4; ++j) {
      int v = t + j * 1024;
      T1[((size_t)k * 64 + b) * V1 + v] = f2bf(fa[v]);
    }
  }
}

// ---------------- conv1 dense + relu + pool -> z0 [b][v2][32] ----------------
__global__ void k_conv1(const u16* __restrict__ T1, const float* __restrict__ W1,
                        const float* __restrict__ b1, float* __restrict__ z0) {
  __shared__ float w1s[800];
  __shared__ float b1s[32];
  const int b = blockIdx.x & 63, uc = blockIdx.x >> 6, t = threadIdx.x;
  for (int idx = t; idx < 800; idx += 256) w1s[idx] = W1[idx];
  if (t < 32) b1s[t] = b1[t];
  __syncthreads();
  const int u = uc * 256 + t;
  float a1[25], a2[25];
#pragma unroll
  for (int k = 0; k < 25; ++k) {
    u32 w = *(const u32*)&T1[((size_t)k * 64 + b) * V1 + 2 * u];
    a1[k] = bf2f((u16)w);
    a2[k] = bf2f((u16)(w >> 16));
  }
  float mout[32];
#pragma unroll
  for (int f = 0; f < 32; ++f) {
    float s1 = b1s[f], s2 = b1s[f];
#pragma unroll
    for (int k = 0; k < 25; ++k) {
      float w = w1s[f * 25 + k];
      s1 = fmaf(a1[k], w, s1);
      s2 = fmaf(a2[k], w, s2);
    }
    mout[f] = fmaxf(fmaxf(s1, 0.f), fmaxf(s2, 0.f));
  }
  float4* dst = (float4*)&z0[((size_t)b * V2 + u) * 32];
#pragma unroll
  for (int q = 0; q < 8; ++q)
    dst[q] = make_float4(mout[4 * q], mout[4 * q + 1], mout[4 * q + 2], mout[4 * q + 3]);
}

// ---------------- layer-2 recurrence: block = (b, fg of 4 fins) ----------------
// TkS[v][4] fp32 (32 KB -> 2 blocks/CU). One ds_read_b128 per edge covers all
// 4 fins; edges loaded once via degree-balanced ELL. T2 layout
// [k*8+fg][m = bl*V2 + v][4fin] bf16 -> contiguous 8B x 64-lane stores.
// NOTE: direct TkS[...] indexing (not runtime pointers) keeps accesses on the
// ds_read path — R10's pointer-swapped dbuf variant regressed 192->345 us.
__global__ void __launch_bounds__(512, 4) k_l2rec(
    const float* __restrict__ z0, const int* __restrict__ rs2,
    const int* __restrict__ rowOf2, const float2* __restrict__ ell2,
    u16* __restrict__ T2, int b0, int bs) {
  __shared__ float TkS[V2 * 4];
  const int bl = blockIdx.x % bs, fg = blockIdx.x / bs;   // fg in [0,8)
  const int b = b0 + bl, f0 = fg * 4;
  const int t = threadIdx.x;
  const size_t M = (size_t)bs * V2;
  const size_t mb = (size_t)bl * V2;
#pragma unroll
  for (int j = 0; j < 4; ++j) {
    int v = t + j * 512;
    float4 xv = *(const float4*)&z0[((size_t)b * V2 + v) * 32 + f0];
    *(float4*)&TkS[v * 4] = xv;
    u32 lo = (u32)f2bf(xv.x) | ((u32)f2bf(xv.y) << 16);
    u32 hi = (u32)f2bf(xv.z) | ((u32)f2bf(xv.w) << 16);
    *(uint2*)&T2[((size_t)fg * M + mb + v) * 4] = make_uint2(lo, hi);
  }
  int vj[4];
#pragma unroll
  for (int j = 0; j < 4; ++j) vj[j] = rowOf2[t + j * 512];
  int bound = rs2[vj[0] + 1] - rs2[vj[0]];
  if (bound > WCAP) bound = WCAP;
  float4 t2r[4];
  __syncthreads();
  for (int k = 1; k < 25; ++k) {
    float4 acc[4];
#pragma unroll
    for (int j = 0; j < 4; ++j) acc[j] = make_float4(0.f, 0.f, 0.f, 0.f);
    for (int w = 0; w < bound; ++w) {
      const float2* ep = ell2 + (size_t)w * V2 + t;
#pragma unroll
      for (int j = 0; j < 4; ++j) {
        float2 ev = ep[j * 512];
        int ub = __float_as_int(ev.y);            // col*16 (byte offset)
        float4 tv = *(const float4*)((const char*)TkS + ub);
        acc[j].x = fmaf(ev.x, tv.x, acc[j].x);
        acc[j].y = fmaf(ev.x, tv.y, acc[j].y);
        acc[j].z = fmaf(ev.x, tv.z, acc[j].z);
        acc[j].w = fmaf(ev.x, tv.w, acc[j].w);
      }
    }
    __syncthreads();
#pragma unroll
    for (int j = 0; j < 4; ++j) {
      float4 old = *(const float4*)&TkS[vj[j] * 4];
      float4 z;
      z.x = acc[j].x - old.x; z.y = acc[j].y - old.y;
      z.z = acc[j].z - old.z; z.w = acc[j].w - old.w;
      if (k > 1) {
        z.x = 2.f * z.x - t2r[j].x; z.y = 2.f * z.y - t2r[j].y;
        z.z = 2.f * z.z - t2r[j].z; z.w = 2.f * z.w - t2r[j].w;
      }
      t2r[j] = old;
      *(float4*)&TkS[vj[j] * 4] = z;
    }
    __syncthreads();
#pragma unroll
    for (int j = 0; j < 4; ++j) {
      int v = t + j * 512;
      float4 zz = *(const float4*)&TkS[v * 4];
      u32 lo = (u32)f2bf(zz.x) | ((u32)f2bf(zz.y) << 16);
      u32 hi = (u32)f2bf(zz.z) | ((u32)f2bf(zz.w) << 16);
      *(uint2*)&T2[(((size_t)k * 8 + fg) * M + mb + v) * 4] = make_uint2(lo, hi);
    }
  }
}

// ---------------- conv2 via MFMA: C = T2 * (Wh+Wl)^T, relu + pool -> h2h/h2l ----------------
__global__ void __launch_bounds__(256) k_conv2mm(
    const u16* __restrict__ T2, const u16* __restrict__ Wh, const u16* __restrict__ Wl,
    const float* __restrict__ b2, u16* __restrict__ h2h, u16* __restrict__ h2l,
    int b0, int bs) {
  const int t = threadIdx.x;
  const int wid = t >> 6, lane = t & 63;
  const int ln = lane & 15, kg = lane >> 4;
  const size_t M = (size_t)bs * V2;
  const int mBlk = blockIdx.x * 128;       // 128 rows per block, never crosses batch
  const int bl = mBlk >> 11;               // /V2
  const int v0 = mBlk & (V2 - 1);
  const int m0 = mBlk + wid * 32;          // wave's 2 strips
  const int vw = v0 + wid * 32;

  f32x4 acc[2][4];
#pragma unroll
  for (int nt = 0; nt < 4; ++nt) {
    float bv = b2[nt * 16 + ln];
    acc[0][nt] = (f32x4){bv, bv, bv, bv};
    acc[1][nt] = acc[0][nt];
  }

  for (int kc = 0; kc < 25; ++kc) {
    const int coff = kc * 32 + kg * 8;
    bf16x8 bh[4], blo[4];
#pragma unroll
    for (int nt = 0; nt < 4; ++nt) {
      bh[nt]  = *(const bf16x8*)(Wh + (size_t)(nt * 16 + ln) * 800 + coff);
      blo[nt] = *(const bf16x8*)(Wl + (size_t)(nt * 16 + ln) * 800 + coff);
    }
#pragma unroll
    for (int sp = 0; sp < 2; ++sp) {
      const u16* ap = T2 + ((size_t)(kc * 8 + kg * 2) * M + (size_t)(m0 + sp * 16 + ln)) * 4;
      uint2 alo = *(const uint2*)ap;
      uint2 ahi = *(const uint2*)(ap + M * 4);   // next fg-slab
      union { uint4 u; bf16x8 v; } ac;
      ac.u = make_uint4(alo.x, alo.y, ahi.x, ahi.y);
#pragma unroll
      for (int nt = 0; nt < 4; ++nt) {
        acc[sp][nt] = __builtin_amdgcn_mfma_f32_16x16x32_bf16(ac.v, bh[nt], acc[sp][nt], 0, 0, 0);
        acc[sp][nt] = __builtin_amdgcn_mfma_f32_16x16x32_bf16(ac.v, blo[nt], acc[sp][nt], 0, 0, 0);
      }
    }
  }
  const int b = b0 + bl;
  u16* hh = h2h + (size_t)b * 65536;
  u16* hl = h2l + (size_t)b * 65536;
#pragma unroll
  for (int sp = 0; sp < 2; ++sp) {
    int u = ((vw + sp * 16) >> 1) + kg * 2;
#pragma unroll
    for (int nt = 0; nt < 4; ++nt) {
      int f = nt * 16 + ln;
      float p0 = fmaxf(fmaxf(acc[sp][nt].x, acc[sp][nt].y), 0.f);
      float p1 = fmaxf(fmaxf(acc[sp][nt].z, acc[sp][nt].w), 0.f);
      u16 h0 = f2bf(p0), h1 = f2bf(p1);
      hh[(size_t)u * 64 + f] = h0;
      hh[(size_t)(u + 1) * 64 + f] = h1;
      hl[(size_t)u * 64 + f] = f2bf(p0 - bf2f(h0));
      hl[(size_t)(u + 1) * 64 + f] = f2bf(p1 - bf2f(h1));
    }
  }
}

// ---------------- fc1 via MFMA: partial products P[ksp][j][b] (no atomics) ----------------
// 64 K-splits of 1024 -> 512 blocks = 2 blocks/CU (was 1) to hide the fW1
// stream latency.
__global__ void __launch_bounds__(256) k_fc1mm(
    const u16* __restrict__ h2h, const u16* __restrict__ h2l,
    const float* __restrict__ fW1, float* __restrict__ P) {
  __shared__ u16 ahS[64 * 128];   // [b][128 k] u16, byte ^= (b&7)<<4
  __shared__ u16 alS[64 * 128];
  const int t = threadIdx.x;
  const int wid = t >> 6, lane = t & 63;
  const int ln = lane & 15, kg = lane >> 4;
  const int jg = blockIdx.x & 7, ksp = blockIdx.x >> 3;   // 8 jg x 64 ksplits
  const int j = (jg * 4 + wid) * 16 + ln;                 // this lane's W row
  const int k0 = ksp * 1024;

  f32x4 acc[4];
#pragma unroll
  for (int bt = 0; bt < 4; ++bt) acc[bt] = (f32x4){0.f, 0.f, 0.f, 0.f};

  for (int sc = 0; sc < 8; ++sc) {
    const int kc = k0 + sc * 128;
    __syncthreads();                       // previous subchunk fully consumed
    for (int idx = t; idx < 1024; idx += 256) {
      int row = idx >> 4, unit = idx & 15;
      int lb = row * 256 + ((unit * 16) ^ ((row & 7) << 4));
      *(uint4*)((char*)ahS + lb) = *(const uint4*)(h2h + (size_t)row * 65536 + kc + unit * 8);
      *(uint4*)((char*)alS + lb) = *(const uint4*)(h2l + (size_t)row * 65536 + kc + unit * 8);
    }
    __syncthreads();
#pragma unroll
    for (int ks = 0; ks < 4; ++ks) {
      const float* wp = fW1 + (size_t)j * 65536 + kc + ks * 32 + kg * 8;
      float4 w0 = *(const float4*)wp;
      float4 w1 = *(const float4*)(wp + 4);
      float wa[8] = {w0.x, w0.y, w0.z, w0.w, w1.x, w1.y, w1.z, w1.w};
      bf16x8 bh, bl;
#pragma unroll
      for (int i = 0; i < 8; ++i) {
        u16 hi = f2bf(wa[i]);
        ((u16*)&bh)[i] = (short)hi;
        ((u16*)&bl)[i] = (short)f2bf(wa[i] - bf2f(hi));
      }
      const int kb = ks * 64 + kg * 16;
#pragma unroll
      for (int bt = 0; bt < 4; ++bt) {
        int row = bt * 16 + ln;
        int lb = row * 256 + (kb ^ ((row & 7) << 4));
        bf16x8 ah = *(const bf16x8*)((const char*)ahS + lb);
        bf16x8 al = *(const bf16x8*)((const char*)alS + lb);
        acc[bt] = __builtin_amdgcn_mfma_f32_16x16x32_bf16(ah, bh, acc[bt], 0, 0, 0);
        acc[bt] = __builtin_amdgcn_mfma_f32_16x16x32_bf16(ah, bl, acc[bt], 0, 0, 0);
        acc[bt] = __builtin_amdgcn_mfma_f32_16x16x32_bf16(al, bh, acc[bt], 0, 0, 0);
      }
    }
  }
#pragma unroll
  for (int bt = 0; bt < 4; ++bt) {
#pragma unroll
    for (int r = 0; r < 4; ++r) {
      P[(size_t)ksp * 32768 + (size_t)j * 64 + bt * 16 + kg * 4 + r] = acc[bt][r];
    }
  }
}

// ---------------- reduce fc1 partials: fc1o[jb] = sum_ksp P[ksp][jb] ----------------
__global__ void k_red(const float* __restrict__ P, float* __restrict__ fc1o) {
  int idx = blockIdx.x * 256 + threadIdx.x;
  float s = 0.f;
  for (int k = 0; k < 64; ++k) s += P[(size_t)k * 32768 + idx];
  fc1o[idx] = s;
}

__global__ void __launch_bounds__(256) k_fc2(
    const float* __restrict__ fc1o, const float* __restrict__ fb1,
    const float* __restrict__ fW2, const float* __restrict__ fb2,
    float* __restrict__ out) {
  __shared__ float red[256];
  const int c = blockIdx.x, t = threadIdx.x;
  const int b = t & 63, g = t >> 6;
  float s = 0.f;
  for (int j = g * 128; j < g * 128 + 128; ++j) {
    float a = fmaxf(fc1o[j * 64 + b] + fb1[j], 0.f);
    s = fmaf(a, fW2[c * 512 + j], s);
  }
  red[t] = s;
  __syncthreads();
  if (t < 64) {
    out[b * 10 + c] = red[t] + red[t + 64] + red[t + 128] + red[t + 192] + fb2[c];
  }
}

extern "C" void kernel_launch(void* const* d_in, const int* in_sizes, int n_in,
                              void* d_out, int out_size, void* d_ws, size_t ws_size,
                              hipStream_t stream) {
  const float* x    = (const float*)d_in[0];
  const int* L1r    = (const int*)d_in[1];
  const int* L1c    = (const int*)d_in[2];
  const float* L1v  = (const float*)d_in[3];
  const int* L2r    = (const int*)d_in[4];
  const int* L2c    = (const int*)d_in[5];
  const float* L2v  = (const float*)d_in[6];
  const float* W1   = (const float*)d_in[7];
  const float* b1   = (const float*)d_in[8];
  const float* W2   = (const float*)d_in[9];
  const float* b2   = (const float*)d_in[10];
  const float* fW1  = (const float*)d_in[11];
  const float* fb1  = (const float*)d_in[12];
  const float* fW2  = (const float*)d_in[13];
  const float* fb2  = (const float*)d_in[14];
  float* out = (float*)d_out;

  float* Wf = (float*)d_ws;
  size_t off = 0;
  auto alloc = [&](size_t n) { float* q = Wf + off; off += n; return q; };
  int* cnt1    = (int*)alloc(4096);
  int* rs1     = (int*)alloc(4104);     // padded to keep 16B alignment downstream
  int* cnt2    = (int*)alloc(2048);
  int* rs2     = (int*)alloc(2056);
  int* slotOf1 = (int*)alloc(4096);
  int* rowOf1  = (int*)alloc(4096);
  int* slotOf2 = (int*)alloc(2048);
  int* rowOf2  = (int*)alloc(2048);
  u16* Wh      = (u16*)alloc(25600);    // [64][800] bf16 hi (overalloc keeps alignment)
  u16* Wl      = (u16*)alloc(25600);    // [64][800] bf16 lo
  float* fc1o  = alloc(32768);
  float2* ell1 = (float2*)alloc((size_t)WCAP * V1 * 2);   // 1.5 MB
  float2* ell2 = (float2*)alloc((size_t)WCAP * V2 * 2);   // 0.75 MB
  float* P     = alloc(64 * 32768);     // fc1 partials, 8 MB
  float* z0    = alloc(4194304);        // [64 b][2048 v][32 f] fp32, 16.8 MB
  u16* h2h     = (u16*)alloc(2097152);  // [64 b][65536 i] bf16 hi, 8.4 MB
  u16* h2l     = (u16*)alloc(2097152);  // [64 b][65536 i] bf16 lo, 8.4 MB
  size_t fixedB = off * 4;

  // Batch split so the bf16 Chebyshev basis T2 fits the workspace.
  int ns = 8;
  for (int c = 1; c <= 8; c <<= 1) {
    size_t t2b = (size_t)V2 * (64 / c) * 800 * 2;
    size_t big = t2b > 16777216ull ? t2b : 16777216ull;   // T1 (12.6 MB) overlays same region
    if (fixedB + big + 65536 <= ws_size) { ns = c; break; }
  }
  const int bs = 64 / ns;
  u16* T1 = (u16*)(Wf + off);           // [k][b][v] bf16
  u16* T2 = (u16*)(Wf + off);           // [k*8+fg][m = bl*V2+v][4fin] bf16 — overlays T1 (dead)

  hipMemsetAsync(cnt1, 0, 4096 * sizeof(int), stream);
  hipMemsetAsync(cnt2, 0, 2048 * sizeof(int), stream);
  hipMemsetAsync(ell1, 0, (size_t)WCAP * V1 * 8, stream);  // padded ELL entries = 0
  hipMemsetAsync(ell2, 0, (size_t)WCAP * V2 * 8, stream);

  k_hist<<<392, 256, 0, stream>>>(L1r, L2r, W2, Wh, Wl, cnt1, cnt2);
  k_scan<<<2, 256, 0, stream>>>(cnt1, rs1, cnt2, rs2, slotOf1, rowOf1, slotOf2, rowOf2);
  k_scatter<<<192, 256, 0, stream>>>(L1r, L1c, L1v, L2r, L2c, L2v,
                                     cnt1, rs1, slotOf1, ell1,
                                     cnt2, rs2, slotOf2, ell2);

  k_l1rec<<<64, 1024, 0, stream>>>(x, rs1, rowOf1, ell1, T1);
  k_conv1<<<512, 256, 0, stream>>>(T1, W1, b1, z0);

  for (int s = 0; s < ns; ++s) {
    int b0 = s * bs;
    k_l2rec<<<bs * 8, 512, 0, stream>>>(z0, rs2, rowOf2, ell2, T2, b0, bs);  // 8 fin-groups of 4
    k_conv2mm<<<bs * 16, 256, 0, stream>>>(T2, Wh, Wl, b2, h2h, h2l, b0, bs);
  }

  k_fc1mm<<<512, 256, 0, stream>>>(h2h, h2l, fW1, P);
  k_red<<<128, 256, 0, stream>>>(P, fc1o);
  k_fc2<<<10, 256, 0, stream>>>(fc1o, fb1, fW2, fb2, out);
}

// Round 12
// 684.236 us; speedup vs baseline: 1.2792x; 1.0159x over previous
//
#include <hip/hip_runtime.h>
#include <hip/hip_bf16.h>

#define V1 4096
#define V2 2048
#define NNZ1 32768
#define NNZ2 16384
#define WCAP 48

typedef unsigned short u16;
typedef unsigned int u32;
typedef __attribute__((ext_vector_type(8))) short bf16x8;
typedef __attribute__((ext_vector_type(4))) float f32x4;

static __device__ __forceinline__ float bf2f(u16 u) {
  union { u32 i; float f; } c; c.i = ((u32)u) << 16; return c.f;
}
static __device__ __forceinline__ u16 f2bf(float f) {
  union { u32 i; float f; } c; c.f = f;
  u32 r = c.i + 0x7FFFu + ((c.i >> 16) & 1u);   // round-nearest-even
  return (u16)(r >> 16);
}

// ---------------- histogram + bf16 hi/lo weight transpose ----------------
// Wh/Wl[f][kap = k*32 + fin] = hi/lo bf16 split of W2[f][fin*25+k]
__global__ void k_hist(const int* __restrict__ L1r, const int* __restrict__ L2r,
                       const float* __restrict__ W2, u16* __restrict__ Wh,
                       u16* __restrict__ Wl,
                       int* __restrict__ cnt1, int* __restrict__ cnt2) {
  int lt = blockIdx.x, t = threadIdx.x;
  if (lt < 128) {
    atomicAdd(&cnt1[L1r[lt * 256 + t]], 1);
  } else if (lt < 192) {
    atomicAdd(&cnt2[L2r[(lt - 128) * 256 + t]], 1);
  } else {
    int idx = (lt - 192) * 256 + t;          // 51200 = 64 f x 800 kap
    int f = idx / 800;
    int kap = idx - f * 800;
    int k = kap >> 5, fin = kap & 31;
    float w = W2[f * 800 + fin * 25 + k];
    u16 hi = f2bf(w);
    Wh[idx] = hi;
    Wl[idx] = f2bf(w - bf2f(hi));
  }
}

// ---------------- scan + degree counting-sort (descending) ----------------
__global__ void k_scan(int* __restrict__ cnt1, int* __restrict__ rs1,
                       int* __restrict__ cnt2, int* __restrict__ rs2,
                       int* __restrict__ slotOf1, int* __restrict__ rowOf1,
                       int* __restrict__ slotOf2, int* __restrict__ rowOf2) {
  __shared__ int sums[256];
  __shared__ int degS[V1];
  __shared__ int hist[64];
  __shared__ int hb[64];
  int t = threadIdx.x;
  int* cnt; int* rs; int* slotOf; int* rowOf; int V, NT, nnz;
  if (blockIdx.x == 0) { cnt = cnt1; rs = rs1; slotOf = slotOf1; rowOf = rowOf1; V = V1; NT = 1024; nnz = NNZ1; }
  else                 { cnt = cnt2; rs = rs2; slotOf = slotOf2; rowOf = rowOf2; V = V2; NT = 512;  nnz = NNZ2; }
  int chunk = V / 256, base = t * chunk, s = 0;
  for (int i = 0; i < chunk; ++i) { int c = cnt[base + i]; degS[base + i] = c; s += c; }
  sums[t] = s;
  if (t < 64) hist[t] = 0;
  __syncthreads();
  if (t == 0) {
    int run = 0;
    for (int i = 0; i < 256; ++i) { int c = sums[i]; sums[i] = run; run += c; }
  }
  __syncthreads();
  int pfx = sums[t];
  for (int i = 0; i < chunk; ++i) {
    int c = degS[base + i];
    rs[base + i] = pfx;
    cnt[base + i] = pfx;                     // cursor for scatter
    pfx += c;
  }
  if (t == 0) rs[V] = nnz;
  for (int i = 0; i < chunk; ++i) {
    int d = degS[base + i]; if (d > 63) d = 63;
    atomicAdd(&hist[d], 1);
  }
  __syncthreads();
  if (t == 0) {
    int run = 0;
    for (int d = 63; d >= 0; --d) { hb[d] = run; run += hist[d]; }
  }
  __syncthreads();
  for (int i = 0; i < chunk; ++i) {
    int v = base + i;
    int d = degS[v]; if (d > 63) d = 63;
    int r = atomicAdd(&hb[d], 1);            // rank, degree-descending
    int slot = (r & 3) * NT + (r >> 2);
    slotOf[v] = slot;
    rowOf[slot] = v;
  }
}

// ---------------- scatter edges directly into zero-padded ELL ----------------
// ell[w*V + slot] = (val, as_float(col*byte_mult)); w = CSR position in row so
// per-row FP summation order matches the reference CSR order exactly.
__global__ void k_scatter(const int* __restrict__ L1r, const int* __restrict__ L1c,
                          const float* __restrict__ L1v,
                          const int* __restrict__ L2r, const int* __restrict__ L2c,
                          const float* __restrict__ L2v,
                          int* __restrict__ cur1, const int* __restrict__ rs1,
                          const int* __restrict__ slotOf1, float2* __restrict__ ell1,
                          int* __restrict__ cur2, const int* __restrict__ rs2,
                          const int* __restrict__ slotOf2, float2* __restrict__ ell2) {
  int lt = blockIdx.x, t = threadIdx.x;
  if (lt < 128) {
    int e = lt * 256 + t;
    int row = L1r[e];
    int pos = atomicAdd(&cur1[row], 1);
    int w = pos - rs1[row];
    if (w < WCAP)
      ell1[(size_t)w * V1 + slotOf1[row]] = make_float2(L1v[e], __int_as_float(L1c[e] * 4));
  } else {
    int e = (lt - 128) * 256 + t;
    int row = L2r[e];
    int pos = atomicAdd(&cur2[row], 1);
    int w = pos - rs2[row];
    if (w < WCAP)
      ell2[(size_t)w * V2 + slotOf2[row]] = make_float2(L2v[e], __int_as_float(L2c[e] * 16));
  }
}

// ---------------- layer-1 recurrence: block = one batch, ELL gather ----------------
__global__ void __launch_bounds__(1024) k_l1rec(
    const float* __restrict__ x, const int* __restrict__ rs1,
    const int* __restrict__ rowOf1, const float2* __restrict__ ell1,
    u16* __restrict__ T1) {
  __shared__ float fa[V1];
  const int b = blockIdx.x, t = threadIdx.x;
#pragma unroll
  for (int j = 0; j < 4; ++j) {
    int v = t + j * 1024;
    float xv = x[(size_t)b * V1 + v];
    fa[v] = xv;
    T1[((size_t)b) * V1 + v] = f2bf(xv);          // slice k=0
  }
  int vj[4];
#pragma unroll
  for (int j = 0; j < 4; ++j) vj[j] = rowOf1[t + j * 1024];
  int bound = rs1[vj[0] + 1] - rs1[vj[0]];
  if (bound > WCAP) bound = WCAP;
  float t2r[4];
  __syncthreads();
  for (int k = 1; k < 25; ++k) {
    float acc[4] = {0.f, 0.f, 0.f, 0.f};
    for (int w = 0; w < bound; ++w) {
      const float2* ep = ell1 + (size_t)w * V1 + t;
#pragma unroll
      for (int j = 0; j < 4; ++j) {
        float2 ev = ep[j * 1024];
        int ub = __float_as_int(ev.y);            // col*4 (byte offset)
        float av = *(const float*)((const char*)fa + ub);
        acc[j] = fmaf(ev.x, av, acc[j]);
      }
    }
    __syncthreads();
#pragma unroll
    for (int j = 0; j < 4; ++j) {
      float old = fa[vj[j]];
      float z = acc[j] - old;                     // coef = 2/lmax = 1
      if (k > 1) z = 2.f * z - t2r[j];
      t2r[j] = old;
      fa[vj[j]] = z;
    }
    __syncthreads();
#pragma unroll
    for (int j = 0; j < 4; ++j) {
      int v = t + j * 1024;
      T1[((size_t)k * 64 + b) * V1 + v] = f2bf(fa[v]);
    }
  }
}

// ---------------- conv1 dense + relu + pool -> z0 [b][v2][32] ----------------
__global__ void k_conv1(const u16* __restrict__ T1, const float* __restrict__ W1,
                        const float* __restrict__ b1, float* __restrict__ z0) {
  __shared__ float w1s[800];
  __shared__ float b1s[32];
  const int b = blockIdx.x & 63, uc = blockIdx.x >> 6, t = threadIdx.x;
  for (int idx = t; idx < 800; idx += 256) w1s[idx] = W1[idx];
  if (t < 32) b1s[t] = b1[t];
  __syncthreads();
  const int u = uc * 256 + t;
  float a1[25], a2[25];
#pragma unroll
  for (int k = 0; k < 25; ++k) {
    u32 w = *(const u32*)&T1[((size_t)k * 64 + b) * V1 + 2 * u];
    a1[k] = bf2f((u16)w);
    a2[k] = bf2f((u16)(w >> 16));
  }
  float mout[32];
#pragma unroll
  for (int f = 0; f < 32; ++f) {
    float s1 = b1s[f], s2 = b1s[f];
#pragma unroll
    for (int k = 0; k < 25; ++k) {
      float w = w1s[f * 25 + k];
      s1 = fmaf(a1[k], w, s1);
      s2 = fmaf(a2[k], w, s2);
    }
    mout[f] = fmaxf(fmaxf(s1, 0.f), fmaxf(s2, 0.f));
  }
  float4* dst = (float4*)&z0[((size_t)b * V2 + u) * 32];
#pragma unroll
  for (int q = 0; q < 8; ++q)
    dst[q] = make_float4(mout[4 * q], mout[4 * q + 1], mout[4 * q + 2], mout[4 * q + 3]);
}

// ---------------- layer-2 recurrence: block = (b, fg of 4 fins) ----------------
// TkS[v][4] fp32 (32 KB -> 2 blocks/CU). One ds_read_b128 per edge covers all
// 4 fins; edges loaded once via degree-balanced ELL. T2 layout
// [k*8+fg][m = bl*V2 + v][4fin] bf16 -> contiguous 8B x 64-lane stores.
// NOTE: direct TkS[...] indexing (not runtime pointers) keeps accesses on the
// ds_read path — R10's pointer-swapped dbuf variant regressed 192->345 us.
__global__ void __launch_bounds__(512, 4) k_l2rec(
    const float* __restrict__ z0, const int* __restrict__ rs2,
    const int* __restrict__ rowOf2, const float2* __restrict__ ell2,
    u16* __restrict__ T2, int b0, int bs) {
  __shared__ float TkS[V2 * 4];
  const int bl = blockIdx.x % bs, fg = blockIdx.x / bs;   // fg in [0,8)
  const int b = b0 + bl, f0 = fg * 4;
  const int t = threadIdx.x;
  const size_t M = (size_t)bs * V2;
  const size_t mb = (size_t)bl * V2;
#pragma unroll
  for (int j = 0; j < 4; ++j) {
    int v = t + j * 512;
    float4 xv = *(const float4*)&z0[((size_t)b * V2 + v) * 32 + f0];
    *(float4*)&TkS[v * 4] = xv;
    u32 lo = (u32)f2bf(xv.x) | ((u32)f2bf(xv.y) << 16);
    u32 hi = (u32)f2bf(xv.z) | ((u32)f2bf(xv.w) << 16);
    *(uint2*)&T2[((size_t)fg * M + mb + v) * 4] = make_uint2(lo, hi);
  }
  int vj[4];
#pragma unroll
  for (int j = 0; j < 4; ++j) vj[j] = rowOf2[t + j * 512];
  int bound = rs2[vj[0] + 1] - rs2[vj[0]];
  if (bound > WCAP) bound = WCAP;
  float4 t2r[4];
  __syncthreads();
  for (int k = 1; k < 25; ++k) {
    float4 acc[4];
#pragma unroll
    for (int j = 0; j < 4; ++j) acc[j] = make_float4(0.f, 0.f, 0.f, 0.f);
    for (int w = 0; w < bound; ++w) {
      const float2* ep = ell2 + (size_t)w * V2 + t;
#pragma unroll
      for (int j = 0; j < 4; ++j) {
        float2 ev = ep[j * 512];
        int ub = __float_as_int(ev.y);            // col*16 (byte offset)
        float4 tv = *(const float4*)((const char*)TkS + ub);
        acc[j].x = fmaf(ev.x, tv.x, acc[j].x);
        acc[j].y = fmaf(ev.x, tv.y, acc[j].y);
        acc[j].z = fmaf(ev.x, tv.z, acc[j].z);
        acc[j].w = fmaf(ev.x, tv.w, acc[j].w);
      }
    }
    __syncthreads();
#pragma unroll
    for (int j = 0; j < 4; ++j) {
      float4 old = *(const float4*)&TkS[vj[j] * 4];
      float4 z;
      z.x = acc[j].x - old.x; z.y = acc[j].y - old.y;
      z.z = acc[j].z - old.z; z.w = acc[j].w - old.w;
      if (k > 1) {
        z.x = 2.f * z.x - t2r[j].x; z.y = 2.f * z.y - t2r[j].y;
        z.z = 2.f * z.z - t2r[j].z; z.w = 2.f * z.w - t2r[j].w;
      }
      t2r[j] = old;
      *(float4*)&TkS[vj[j] * 4] = z;
    }
    __syncthreads();
#pragma unroll
    for (int j = 0; j < 4; ++j) {
      int v = t + j * 512;
      float4 zz = *(const float4*)&TkS[v * 4];
      u32 lo = (u32)f2bf(zz.x) | ((u32)f2bf(zz.y) << 16);
      u32 hi = (u32)f2bf(zz.z) | ((u32)f2bf(zz.w) << 16);
      *(uint2*)&T2[(((size_t)k * 8 + fg) * M + mb + v) * 4] = make_uint2(lo, hi);
    }
  }
}

// ---------------- conv2 via MFMA: C = T2 * (Wh+Wl)^T, relu + pool -> h2h/h2l ----------------
__global__ void __launch_bounds__(256) k_conv2mm(
    const u16* __restrict__ T2, const u16* __restrict__ Wh, const u16* __restrict__ Wl,
    const float* __restrict__ b2, u16* __restrict__ h2h, u16* __restrict__ h2l,
    int b0, int bs) {
  const int t = threadIdx.x;
  const int wid = t >> 6, lane = t & 63;
  const int ln = lane & 15, kg = lane >> 4;
  const size_t M = (size_t)bs * V2;
  const int mBlk = blockIdx.x * 128;       // 128 rows per block, never crosses batch
  const int bl = mBlk >> 11;               // /V2
  const int v0 = mBlk & (V2 - 1);
  const int m0 = mBlk + wid * 32;          // wave's 2 strips
  const int vw = v0 + wid * 32;

  f32x4 acc[2][4];
#pragma unroll
  for (int nt = 0; nt < 4; ++nt) {
    float bv = b2[nt * 16 + ln];
    acc[0][nt] = (f32x4){bv, bv, bv, bv};
    acc[1][nt] = acc[0][nt];
  }

  for (int kc = 0; kc < 25; ++kc) {
    const int coff = kc * 32 + kg * 8;
    bf16x8 bh[4], blo[4];
#pragma unroll
    for (int nt = 0; nt < 4; ++nt) {
      bh[nt]  = *(const bf16x8*)(Wh + (size_t)(nt * 16 + ln) * 800 + coff);
      blo[nt] = *(const bf16x8*)(Wl + (size_t)(nt * 16 + ln) * 800 + coff);
    }
#pragma unroll
    for (int sp = 0; sp < 2; ++sp) {
      const u16* ap = T2 + ((size_t)(kc * 8 + kg * 2) * M + (size_t)(m0 + sp * 16 + ln)) * 4;
      uint2 alo = *(const uint2*)ap;
      uint2 ahi = *(const uint2*)(ap + M * 4);   // next fg-slab
      union { uint4 u; bf16x8 v; } ac;
      ac.u = make_uint4(alo.x, alo.y, ahi.x, ahi.y);
#pragma unroll
      for (int nt = 0; nt < 4; ++nt) {
        acc[sp][nt] = __builtin_amdgcn_mfma_f32_16x16x32_bf16(ac.v, bh[nt], acc[sp][nt], 0, 0, 0);
        acc[sp][nt] = __builtin_amdgcn_mfma_f32_16x16x32_bf16(ac.v, blo[nt], acc[sp][nt], 0, 0, 0);
      }
    }
  }
  const int b = b0 + bl;
  u16* hh = h2h + (size_t)b * 65536;
  u16* hl = h2l + (size_t)b * 65536;
#pragma unroll
  for (int sp = 0; sp < 2; ++sp) {
    int u = ((vw + sp * 16) >> 1) + kg * 2;
#pragma unroll
    for (int nt = 0; nt < 4; ++nt) {
      int f = nt * 16 + ln;
      float p0 = fmaxf(fmaxf(acc[sp][nt].x, acc[sp][nt].y), 0.f);
      float p1 = fmaxf(fmaxf(acc[sp][nt].z, acc[sp][nt].w), 0.f);
      u16 h0 = f2bf(p0), h1 = f2bf(p1);
      hh[(size_t)u * 64 + f] = h0;
      hh[(size_t)(u + 1) * 64 + f] = h1;
      hl[(size_t)u * 64 + f] = f2bf(p0 - bf2f(h0));
      hl[(size_t)(u + 1) * 64 + f] = f2bf(p1 - bf2f(h1));
    }
  }
}

// ---------------- fc1 via MFMA: partial products P[ksp][j][b] (no atomics) ----------------
// Block = 8 waves x 16 j = 128 j (4 j-groups -> h2 re-read 4x, was 8x);
// 128 K-splits of 512 -> 512 blocks = 2 blocks/CU, 16 waves/CU.
__global__ void __launch_bounds__(512) k_fc1mm(
    const u16* __restrict__ h2h, const u16* __restrict__ h2l,
    const float* __restrict__ fW1, float* __restrict__ P) {
  __shared__ u16 ahS[64 * 128];   // [b][128 k] u16, byte ^= (b&7)<<4
  __shared__ u16 alS[64 * 128];
  const int t = threadIdx.x;
  const int wid = t >> 6, lane = t & 63;
  const int ln = lane & 15, kg = lane >> 4;
  const int jg = blockIdx.x & 3, ksp = blockIdx.x >> 2;   // 4 jg x 128 ksplits
  const int j = (jg * 8 + wid) * 16 + ln;                 // this lane's W row
  const int k0 = ksp * 512;

  f32x4 acc[4];
#pragma unroll
  for (int bt = 0; bt < 4; ++bt) acc[bt] = (f32x4){0.f, 0.f, 0.f, 0.f};

  for (int sc = 0; sc < 4; ++sc) {
    const int kc = k0 + sc * 128;
    __syncthreads();                       // previous subchunk fully consumed
    for (int idx = t; idx < 1024; idx += 512) {
      int row = idx >> 4, unit = idx & 15;
      int lb = row * 256 + ((unit * 16) ^ ((row & 7) << 4));
      *(uint4*)((char*)ahS + lb) = *(const uint4*)(h2h + (size_t)row * 65536 + kc + unit * 8);
      *(uint4*)((char*)alS + lb) = *(const uint4*)(h2l + (size_t)row * 65536 + kc + unit * 8);
    }
    __syncthreads();
#pragma unroll
    for (int ks = 0; ks < 4; ++ks) {
      const float* wp = fW1 + (size_t)j * 65536 + kc + ks * 32 + kg * 8;
      float4 w0 = *(const float4*)wp;
      float4 w1 = *(const float4*)(wp + 4);
      float wa[8] = {w0.x, w0.y, w0.z, w0.w, w1.x, w1.y, w1.z, w1.w};
      bf16x8 bh, bl;
#pragma unroll
      for (int i = 0; i < 8; ++i) {
        u16 hi = f2bf(wa[i]);
        ((u16*)&bh)[i] = (short)hi;
        ((u16*)&bl)[i] = (short)f2bf(wa[i] - bf2f(hi));
      }
      const int kb = ks * 64 + kg * 16;
#pragma unroll
      for (int bt = 0; bt < 4; ++bt) {
        int row = bt * 16 + ln;
        int lb = row * 256 + (kb ^ ((row & 7) << 4));
        bf16x8 ah = *(const bf16x8*)((const char*)ahS + lb);
        bf16x8 al = *(const bf16x8*)((const char*)alS + lb);
        acc[bt] = __builtin_amdgcn_mfma_f32_16x16x32_bf16(ah, bh, acc[bt], 0, 0, 0);
        acc[bt] = __builtin_amdgcn_mfma_f32_16x16x32_bf16(ah, bl, acc[bt], 0, 0, 0);
        acc[bt] = __builtin_amdgcn_mfma_f32_16x16x32_bf16(al, bh, acc[bt], 0, 0, 0);
      }
    }
  }
#pragma unroll
  for (int bt = 0; bt < 4; ++bt) {
#pragma unroll
    for (int r = 0; r < 4; ++r) {
      P[(size_t)ksp * 32768 + (size_t)j * 64 + bt * 16 + kg * 4 + r] = acc[bt][r];
    }
  }
}

// ---------------- reduce fc1 partials: fc1o[jb] = sum_ksp P[ksp][jb] ----------------
__global__ void k_red(const float* __restrict__ P, float* __restrict__ fc1o) {
  int idx = blockIdx.x * 256 + threadIdx.x;
  float s = 0.f;
  for (int k = 0; k < 128; ++k) s += P[(size_t)k * 32768 + idx];
  fc1o[idx] = s;
}

__global__ void __launch_bounds__(256) k_fc2(
    const float* __restrict__ fc1o, const float* __restrict__ fb1,
    const float* __restrict__ fW2, const float* __restrict__ fb2,
    float* __restrict__ out) {
  __shared__ float red[256];
  const int c = blockIdx.x, t = threadIdx.x;
  const int b = t & 63, g = t >> 6;
  float s = 0.f;
  for (int j = g * 128; j < g * 128 + 128; ++j) {
    float a = fmaxf(fc1o[j * 64 + b] + fb1[j], 0.f);
    s = fmaf(a, fW2[c * 512 + j], s);
  }
  red[t] = s;
  __syncthreads();
  if (t < 64) {
    out[b * 10 + c] = red[t] + red[t + 64] + red[t + 128] + red[t + 192] + fb2[c];
  }
}

extern "C" void kernel_launch(void* const* d_in, const int* in_sizes, int n_in,
                              void* d_out, int out_size, void* d_ws, size_t ws_size,
                              hipStream_t stream) {
  const float* x    = (const float*)d_in[0];
  const int* L1r    = (const int*)d_in[1];
  const int* L1c    = (const int*)d_in[2];
  const float* L1v  = (const float*)d_in[3];
  const int* L2r    = (const int*)d_in[4];
  const int* L2c    = (const int*)d_in[5];
  const float* L2v  = (const float*)d_in[6];
  const float* W1   = (const float*)d_in[7];
  const float* b1   = (const float*)d_in[8];
  const float* W2   = (const float*)d_in[9];
  const float* b2   = (const float*)d_in[10];
  const float* fW1  = (const float*)d_in[11];
  const float* fb1  = (const float*)d_in[12];
  const float* fW2  = (const float*)d_in[13];
  const float* fb2  = (const float*)d_in[14];
  float* out = (float*)d_out;

  float* Wf = (float*)d_ws;
  size_t off = 0;
  auto alloc = [&](size_t n) { float* q = Wf + off; off += n; return q; };
  int* cnt1    = (int*)alloc(4096);
  int* rs1     = (int*)alloc(4104);     // padded to keep 16B alignment downstream
  int* cnt2    = (int*)alloc(2048);
  int* rs2     = (int*)alloc(2056);
  int* slotOf1 = (int*)alloc(4096);
  int* rowOf1  = (int*)alloc(4096);
  int* slotOf2 = (int*)alloc(2048);
  int* rowOf2  = (int*)alloc(2048);
  u16* Wh      = (u16*)alloc(25600);    // [64][800] bf16 hi (overalloc keeps alignment)
  u16* Wl      = (u16*)alloc(25600);    // [64][800] bf16 lo
  float* fc1o  = alloc(32768);
  float2* ell1 = (float2*)alloc((size_t)WCAP * V1 * 2);   // 1.5 MB
  float2* ell2 = (float2*)alloc((size_t)WCAP * V2 * 2);   // 0.75 MB
  float* z0    = alloc(4194304);        // [64 b][2048 v][32 f] fp32, 16.8 MB
  u16* h2h     = (u16*)alloc(2097152);  // [64 b][65536 i] bf16 hi, 8.4 MB
  u16* h2l     = (u16*)alloc(2097152);  // [64 b][65536 i] bf16 lo, 8.4 MB
  float* P     = z0;                    // fc1 partials (16 MB) alias dead z0:
                                        // z0's last reader is the final l2rec,
                                        // which completes before k_fc1mm runs.
  size_t fixedB = off * 4;

  // Batch split so the bf16 Chebyshev basis T2 fits the workspace.
  int ns = 8;
  for (int c = 1; c <= 8; c <<= 1) {
    size_t t2b = (size_t)V2 * (64 / c) * 800 * 2;
    size_t big = t2b > 16777216ull ? t2b : 16777216ull;   // T1 (12.6 MB) overlays same region
    if (fixedB + big + 65536 <= ws_size) { ns = c; break; }
  }
  const int bs = 64 / ns;
  u16* T1 = (u16*)(Wf + off);           // [k][b][v] bf16
  u16* T2 = (u16*)(Wf + off);           // [k*8+fg][m = bl*V2+v][4fin] bf16 — overlays T1 (dead)

  hipMemsetAsync(cnt1, 0, 4096 * sizeof(int), stream);
  hipMemsetAsync(cnt2, 0, 2048 * sizeof(int), stream);
  hipMemsetAsync(ell1, 0, (size_t)WCAP * V1 * 8, stream);  // padded ELL entries = 0
  hipMemsetAsync(ell2, 0, (size_t)WCAP * V2 * 8, stream);

  k_hist<<<392, 256, 0, stream>>>(L1r, L2r, W2, Wh, Wl, cnt1, cnt2);
  k_scan<<<2, 256, 0, stream>>>(cnt1, rs1, cnt2, rs2, slotOf1, rowOf1, slotOf2, rowOf2);
  k_scatter<<<192, 256, 0, stream>>>(L1r, L1c, L1v, L2r, L2c, L2v,
                                     cnt1, rs1, slotOf1, ell1,
                                     cnt2, rs2, slotOf2, ell2);

  k_l1rec<<<64, 1024, 0, stream>>>(x, rs1, rowOf1, ell1, T1);
  k_conv1<<<512, 256, 0, stream>>>(T1, W1, b1, z0);

  for (int s = 0; s < ns; ++s) {
    int b0 = s * bs;
    k_l2rec<<<bs * 8, 512, 0, stream>>>(z0, rs2, rowOf2, ell2, T2, b0, bs);  // 8 fin-groups of 4
    k_conv2mm<<<bs * 16, 256, 0, stream>>>(T2, Wh, Wl, b2, h2h, h2l, b0, bs);
  }

  k_fc1mm<<<512, 512, 0, stream>>>(h2h, h2l, fW1, P);
  k_red<<<128, 256, 0, stream>>>(P, fc1o);
  k_fc2<<<10, 256, 0, stream>>>(fc1o, fb1, fW2, fb2, out);
}